// Round 1
// baseline (338.175 us; speedup 1.0000x reference)
//
#include <hip/hip_runtime.h>
#include <cmath>

// QKVAttention: score = (Q K^T)/8 causal-masked -> softmax -> out = attn * V (elementwise)
// Outputs: d_out = [out (B,H,S,S) | attn (B,H,S,S)], f32.
// B=2 H=12 S=2048 D=64. Memory-bound: ~1.05 GB mandatory HBM traffic.
//
// One WG (256 thr, 4 waves) per (head, 8-row block). Wave owns 2 full rows ->
// softmax is wave-local. Scores kept in 64 VGPRs/thread (statically indexed).
// K staged per 256-col tile into LDS transposed [d][j] (pitch 260: b128 reads
// conflict-free, writes 2-way). Causal tiles beyond the block diagonal are
// skipped (compute + v reads); their outputs are zero-filled.

#define SDIM 2048
#define DDIM 64
#define RT 8          // rows per workgroup
#define NGROUP 8      // 2048 / 256 col groups
#define GCOLS 256     // cols per staged tile
#define KP 260        // k_lds pitch in floats (mult of 4 for float4 align)
#define BHCOUNT 24    // B*H

__global__ __launch_bounds__(256, 2)
void qkv_attn_fused(const float* __restrict__ q,
                    const float* __restrict__ k,
                    const float* __restrict__ v,
                    float* __restrict__ outp,
                    float* __restrict__ attnp) {
  __shared__ float k_lds[DDIM][KP];   // 66560 B
  __shared__ float q_lds[RT][DDIM];   //  2048 B

  const int t    = threadIdx.x;
  const int wave = t >> 6;
  const int lane = t & 63;

  const int wg = blockIdx.x;
  const int rb = wg & 255;        // row block within head
  const int bh = wg >> 8;         // 0..23
  const int r0 = rb * RT;
  const int gmax = (r0 + RT - 1) >> 8;   // last col-group that intersects causal region

  const int row0 = r0 + 2 * wave;
  const int row1 = row0 + 1;

  // ---- stage q block (8 rows x 64) ----
  if (t < RT * DDIM / 4) {
    const float4* qsrc = (const float4*)(q + ((size_t)bh * SDIM + r0) * DDIM);
    ((float4*)q_lds)[t] = qsrc[t];
  }

  // ---- phase 1: scores in registers ----
  float sc[NGROUP][2][4];
#pragma unroll
  for (int g = 0; g < NGROUP; ++g)
#pragma unroll
    for (int r = 0; r < 2; ++r)
#pragma unroll
      for (int e = 0; e < 4; ++e) sc[g][r][e] = 0.f;

  const float* kbh = k + (size_t)bh * SDIM * DDIM;

#pragma unroll
  for (int g = 0; g < NGROUP; ++g) {
    if (g <= gmax) {                       // WG-uniform guard (barriers legal)
      __syncthreads();                     // protect k_lds reuse; covers q_lds for g==0
      // stage k tile: cols [256g, 256g+256) transposed into k_lds[d][j]
      const float* kbase = kbh + (size_t)g * GCOLS * DDIM;
#pragma unroll
      for (int it = 0; it < 16; ++it) {
        const int jt = it & 3, dt = it >> 2;
        const int j  = (t >> 2) + 64 * jt;        // 0..255
        const int d4 = (t & 3) + 4 * dt;          // 0..15
        const float4 kv = *(const float4*)(kbase + (size_t)j * DDIM + 4 * d4);
        k_lds[4 * d4 + 0][j] = kv.x;
        k_lds[4 * d4 + 1][j] = kv.y;
        k_lds[4 * d4 + 2][j] = kv.z;
        k_lds[4 * d4 + 3][j] = kv.w;
      }
      __syncthreads();
      // dot products: lane owns cols 4*lane..4*lane+3 of this tile, 2 rows
#pragma unroll 8
      for (int d = 0; d < DDIM; ++d) {
        const float4 kv = *(const float4*)&k_lds[d][4 * lane];
        const float q0 = q_lds[2 * wave][d];
        const float q1 = q_lds[2 * wave + 1][d];
        sc[g][0][0] = fmaf(q0, kv.x, sc[g][0][0]);
        sc[g][0][1] = fmaf(q0, kv.y, sc[g][0][1]);
        sc[g][0][2] = fmaf(q0, kv.z, sc[g][0][2]);
        sc[g][0][3] = fmaf(q0, kv.w, sc[g][0][3]);
        sc[g][1][0] = fmaf(q1, kv.x, sc[g][1][0]);
        sc[g][1][1] = fmaf(q1, kv.y, sc[g][1][1]);
        sc[g][1][2] = fmaf(q1, kv.z, sc[g][1][2]);
        sc[g][1][3] = fmaf(q1, kv.w, sc[g][1][3]);
      }
    }
  }

  // ---- softmax (wave-local per row) ----
  const float NEGBIG = -3.0e38f;
  float m0 = NEGBIG, m1 = NEGBIG;
#pragma unroll
  for (int g = 0; g < NGROUP; ++g) {
    if (g <= gmax) {
#pragma unroll
      for (int e = 0; e < 4; ++e) {
        const int col = GCOLS * g + 4 * lane + e;
        sc[g][0][e] *= 0.125f;             // 1/sqrt(64)
        sc[g][1][e] *= 0.125f;
        if (col <= row0) m0 = fmaxf(m0, sc[g][0][e]);
        if (col <= row1) m1 = fmaxf(m1, sc[g][1][e]);
      }
    }
  }
#pragma unroll
  for (int off = 32; off > 0; off >>= 1) {
    m0 = fmaxf(m0, __shfl_xor(m0, off, 64));
    m1 = fmaxf(m1, __shfl_xor(m1, off, 64));
  }

  float l0 = 0.f, l1 = 0.f;
#pragma unroll
  for (int g = 0; g < NGROUP; ++g) {
    if (g <= gmax) {
#pragma unroll
      for (int e = 0; e < 4; ++e) {
        const int col = GCOLS * g + 4 * lane + e;
        const float e0 = (col <= row0) ? expf(sc[g][0][e] - m0) : 0.f;
        const float e1 = (col <= row1) ? expf(sc[g][1][e] - m1) : 0.f;
        sc[g][0][e] = e0;  l0 += e0;
        sc[g][1][e] = e1;  l1 += e1;
      }
    }
  }
#pragma unroll
  for (int off = 32; off > 0; off >>= 1) {
    l0 += __shfl_xor(l0, off, 64);
    l1 += __shfl_xor(l1, off, 64);
  }
  const float rl0 = 1.0f / l0;
  const float rl1 = 1.0f / l1;

  // ---- phase 2: attn & out writes ----
  const size_t ob0 = ((size_t)bh * SDIM + row0) * SDIM;
  const size_t ob1 = ob0 + SDIM;

#pragma unroll
  for (int g = 0; g < NGROUP; ++g) {
    const int coff = GCOLS * g + 4 * lane;
    if (g <= gmax) {
      float4 a0, a1;
      a0.x = sc[g][0][0] * rl0;  a0.y = sc[g][0][1] * rl0;
      a0.z = sc[g][0][2] * rl0;  a0.w = sc[g][0][3] * rl0;
      a1.x = sc[g][1][0] * rl1;  a1.y = sc[g][1][1] * rl1;
      a1.z = sc[g][1][2] * rl1;  a1.w = sc[g][1][3] * rl1;
      const float4 v0 = *(const float4*)(v + ob0 + coff);
      const float4 v1 = *(const float4*)(v + ob1 + coff);
      float4 o0, o1;
      o0.x = a0.x * v0.x;  o0.y = a0.y * v0.y;
      o0.z = a0.z * v0.z;  o0.w = a0.w * v0.w;
      o1.x = a1.x * v1.x;  o1.y = a1.y * v1.y;
      o1.z = a1.z * v1.z;  o1.w = a1.w * v1.w;
      *(float4*)(attnp + ob0 + coff) = a0;
      *(float4*)(attnp + ob1 + coff) = a1;
      *(float4*)(outp  + ob0 + coff) = o0;
      *(float4*)(outp  + ob1 + coff) = o1;
    } else {
      const float4 z = make_float4(0.f, 0.f, 0.f, 0.f);
      *(float4*)(attnp + ob0 + coff) = z;
      *(float4*)(attnp + ob1 + coff) = z;
      *(float4*)(outp  + ob0 + coff) = z;
      *(float4*)(outp  + ob1 + coff) = z;
    }
  }
}

extern "C" void kernel_launch(void* const* d_in, const int* in_sizes, int n_in,
                              void* d_out, int out_size, void* d_ws, size_t ws_size,
                              hipStream_t stream) {
  const float* q = (const float*)d_in[0];
  const float* k = (const float*)d_in[1];
  const float* v = (const float*)d_in[2];
  // d_in[3] = mask: fixed causal triu, handled analytically in-kernel.
  float* outp  = (float*)d_out;
  float* attnp = outp + (size_t)BHCOUNT * SDIM * SDIM;

  dim3 grid(BHCOUNT * (SDIM / RT));   // 6144 WGs
  dim3 block(256);
  qkv_attn_fused<<<grid, block, 0, stream>>>(q, k, v, outp, attnp);
}